// Round 16
// baseline (614.409 us; speedup 1.0000x reference)
//
#include <hip/hip_runtime.h>

typedef __attribute__((ext_vector_type(8))) short short8;
typedef __attribute__((ext_vector_type(4))) float f32x4;
typedef __attribute__((ext_vector_type(4))) unsigned short u16x4;

__device__ __forceinline__ unsigned short f2bf(float f){
  unsigned int u = __builtin_bit_cast(unsigned int, f);
  u = (u + 0x7FFFu + ((u >> 16) & 1u)) >> 16;
  return (unsigned short)u;
}
__device__ __forceinline__ float bf2f(unsigned short h){
  unsigned int u = ((unsigned int)h) << 16;
  return __builtin_bit_cast(float, u);
}
__device__ __forceinline__ f32x4 mfma16(short8 a, short8 b, f32x4 c){
  return __builtin_amdgcn_mfma_f32_16x16x32_bf16(a, b, c, 0, 0, 0);
}
// async global->LDS, 16B/lane; lds base wave-uniform (HW: base + lane*16)
__device__ __forceinline__ void gload16(const void* g, void* l){
  __builtin_amdgcn_global_load_lds((const __attribute__((address_space(1))) void*)g,
                                   (__attribute__((address_space(3))) void*)l, 16, 0, 0);
}

// ---------------- f32 -> bf16 conversion, two 512x512 matrices ------------
__global__ __launch_bounds__(256) void cvt2_f32_bf16(const float* __restrict__ s0,
                                                     unsigned short* __restrict__ d0,
                                                     const float* __restrict__ s1,
                                                     unsigned short* __restrict__ d1){
  const int half = blockIdx.x >> 8;
  const float* src = half ? s1 : s0;
  unsigned short* dst = half ? d1 : d0;
  int i = ((blockIdx.x & 255) * 256 + threadIdx.x) * 4;
  float4 v = *(const float4*)(src + i);
  u16x4 o = { f2bf(v.x), f2bf(v.y), f2bf(v.z), f2bf(v.w) };
  *(u16x4*)(dst + i) = o;
}

// ---------------- bf16 copy (524288 elems) --------------------------------
__global__ __launch_bounds__(256) void copy_bf(const unsigned short* __restrict__ src,
                                               unsigned short* __restrict__ dst){
  int i = (blockIdx.x * 256 + threadIdx.x) * 8;
  *(short8*)(dst + i) = *(const short8*)(src + i);
}

// ---------------- LayerNorm over D=512, one wave per row, bf16 out --------
__global__ __launch_bounds__(256) void ln_rows(const float* __restrict__ x,
                                               const float* __restrict__ g,
                                               const float* __restrict__ b,
                                               unsigned short* __restrict__ y,
                                               int nrows){
  const int wid = threadIdx.x >> 6, lane = threadIdx.x & 63;
  const int row = blockIdx.x * 4 + wid;
  if (row >= nrows) return;
  const float* xr = x + (long)row * 512;
  float4 v0 = *(const float4*)(xr + lane * 4);
  float4 v1 = *(const float4*)(xr + 256 + lane * 4);
  float s  = v0.x + v0.y + v0.z + v0.w + v1.x + v1.y + v1.z + v1.w;
  float s2 = v0.x*v0.x + v0.y*v0.y + v0.z*v0.z + v0.w*v0.w
           + v1.x*v1.x + v1.y*v1.y + v1.z*v1.z + v1.w*v1.w;
  #pragma unroll
  for (int m = 1; m < 64; m <<= 1){ s += __shfl_xor(s, m); s2 += __shfl_xor(s2, m); }
  const float mu = s * (1.f/512.f);
  const float rstd = rsqrtf(s2 * (1.f/512.f) - mu*mu + 1e-5f);
  float4 g0 = *(const float4*)(g + lane*4), g1 = *(const float4*)(g + 256 + lane*4);
  float4 b0 = *(const float4*)(b + lane*4), b1 = *(const float4*)(b + 256 + lane*4);
  u16x4 o0 = { f2bf((v0.x-mu)*rstd*g0.x + b0.x), f2bf((v0.y-mu)*rstd*g0.y + b0.y),
               f2bf((v0.z-mu)*rstd*g0.z + b0.z), f2bf((v0.w-mu)*rstd*g0.w + b0.w) };
  u16x4 o1 = { f2bf((v1.x-mu)*rstd*g1.x + b1.x), f2bf((v1.y-mu)*rstd*g1.y + b1.y),
               f2bf((v1.z-mu)*rstd*g1.z + b1.z), f2bf((v1.w-mu)*rstd*g1.w + b1.w) };
  *(u16x4*)(y + (long)row * 512 + lane * 4) = o0;
  *(u16x4*)(y + (long)row * 512 + 256 + lane * 4) = o1;
}

// ---- prep: Wl'[n][c]=Wl[n][c]*g2[c] (bf16); u[n]=sum Wl'; v[n]=Wl.b2+bl;
//      bias_cat[n]=bo[n]; bias_cat[512+n]=c2[n]=sum Wl'[n][c]*bo[c] ---------
__global__ __launch_bounds__(256) void ln_weight_prep(
    const float* __restrict__ Wl, const float* __restrict__ g2,
    const float* __restrict__ b2, const float* __restrict__ bl,
    const float* __restrict__ bo,
    unsigned short* __restrict__ wlp, float* __restrict__ u,
    float* __restrict__ v, float* __restrict__ bias_cat){
  const int wid = threadIdx.x >> 6, lane = threadIdx.x & 63;
  const int n = blockIdx.x * 4 + wid;
  const float* row = Wl + (long)n * 512;
  float su = 0.f, sv = 0.f, sc = 0.f;
  #pragma unroll
  for (int h = 0; h < 2; ++h){
    const int c0 = h * 256 + lane * 4;
    float4 w  = *(const float4*)(row + c0);
    float4 gg = *(const float4*)(g2 + c0);
    float4 bb = *(const float4*)(b2 + c0);
    float4 oo = *(const float4*)(bo + c0);
    float4 wp = { w.x*gg.x, w.y*gg.y, w.z*gg.z, w.w*gg.w };
    su += wp.x + wp.y + wp.z + wp.w;
    sv += w.x*bb.x + w.y*bb.y + w.z*bb.z + w.w*bb.w;
    sc += wp.x*oo.x + wp.y*oo.y + wp.z*oo.z + wp.w*oo.w;
    u16x4 o = { f2bf(wp.x), f2bf(wp.y), f2bf(wp.z), f2bf(wp.w) };
    *(u16x4*)(wlp + (long)n * 512 + c0) = o;
  }
  #pragma unroll
  for (int m = 1; m < 64; m <<= 1){
    su += __shfl_xor(su, m); sv += __shfl_xor(sv, m); sc += __shfl_xor(sc, m);
  }
  if (lane == 0){
    u[n] = su;
    v[n] = sv + bl[n];
    bias_cat[n] = bo[n];
    bias_cat[512 + n] = sc;
  }
}

// ---- cvb: bias_cat[n] += dot(Bcat[n] (bf16,512), bv) ---------------------
__global__ __launch_bounds__(256) void cvb_add(const unsigned short* __restrict__ Bc,
                                               const float* __restrict__ bv,
                                               float* __restrict__ bias_cat){
  const int wid = threadIdx.x >> 6, lane = threadIdx.x & 63;
  const int n = blockIdx.x * 4 + wid;   // 0..1023
  const unsigned short* row = Bc + (long)n * 512;
  short8 a = *(const short8*)(row + lane * 8);
  float s = 0.f;
  #pragma unroll
  for (int j = 0; j < 8; ++j) s += bf2f((unsigned short)a[j]) * bv[lane*8 + j];
  #pragma unroll
  for (int m = 1; m < 64; m <<= 1) s += __shfl_xor(s, m);
  if (lane == 0) bias_cat[n] += s;
}

// ---- transpose three 512x512: dst[k][c] = bf16(src[c][k]) ----------------
__global__ __launch_bounds__(256) void transpose3_bf(
    const float* __restrict__ s0, unsigned short* __restrict__ d0,
    const float* __restrict__ s1, unsigned short* __restrict__ d1,
    const float* __restrict__ s2, unsigned short* __restrict__ d2){
  __shared__ float tile[64][65];
  const float* src = (blockIdx.z == 0) ? s0 : (blockIdx.z == 1) ? s1 : s2;
  unsigned short* dst = (blockIdx.z == 0) ? d0 : (blockIdx.z == 1) ? d1 : d2;
  const int t = threadIdx.x;
  const int k0 = blockIdx.x * 64, c0 = blockIdx.y * 64;
  const int j = t & 63, i = t >> 6;
  #pragma unroll
  for (int rr = 0; rr < 16; ++rr)
    tile[i + rr*4][j] = src[(long)(c0 + i + rr*4) * 512 + k0 + j];
  __syncthreads();
  #pragma unroll
  for (int rr = 0; rr < 16; ++rr)
    dst[(long)(k0 + i + rr*4) * 512 + c0 + j] = f2bf(tile[j][i + rr*4]);
}

// ---------------- C = A(rows x 512) * B(512 x 512)^T + bias ---------------
__global__ __launch_bounds__(256) void gemm_bt(const unsigned short* __restrict__ A,
                                               const unsigned short* __restrict__ B,
                                               const float* __restrict__ bias,
                                               unsigned short* __restrict__ out,
                                               int transposed){
  __shared__ unsigned short At[128][40];
  __shared__ unsigned short Bt[128][40];
  const int t = threadIdx.x, lane = t & 63, wid = t >> 6;
  const int l15 = lane & 15, l4 = lane >> 4;
  const int wr = wid >> 1, wc = wid & 1;
  const int rowBase = blockIdx.y * 128;
  const int colBase = blockIdx.x * 128;
  f32x4 zero = {0.f, 0.f, 0.f, 0.f};
  f32x4 acc[4][4];
  #pragma unroll
  for (int i = 0; i < 4; ++i)
    #pragma unroll
    for (int j = 0; j < 4; ++j) acc[i][j] = zero;
  const int sr = t >> 1, sh = (t & 1) * 16;
  for (int ks = 0; ks < 16; ++ks){
    const int k0 = ks * 32;
    const unsigned short* sa = A + (long)(rowBase + sr) * 512 + k0 + sh;
    *(short8*)&At[sr][sh]     = *(const short8*)sa;
    *(short8*)&At[sr][sh + 8] = *(const short8*)(sa + 8);
    const unsigned short* sb = B + (long)(colBase + sr) * 512 + k0 + sh;
    *(short8*)&Bt[sr][sh]     = *(const short8*)sb;
    *(short8*)&Bt[sr][sh + 8] = *(const short8*)(sb + 8);
    __syncthreads();
    short8 af[4], bfv[4];
    #pragma unroll
    for (int i = 0; i < 4; ++i) af[i]  = *(const short8*)&At[wr*64 + i*16 + l15][l4*8];
    #pragma unroll
    for (int i = 0; i < 4; ++i) bfv[i] = *(const short8*)&Bt[wc*64 + i*16 + l15][l4*8];
    #pragma unroll
    for (int i = 0; i < 4; ++i)
      #pragma unroll
      for (int j = 0; j < 4; ++j)
        acc[i][j] = mfma16(af[i], bfv[j], acc[i][j]);
    __syncthreads();
  }
  #pragma unroll
  for (int i = 0; i < 4; ++i){
    const int r0 = rowBase + wr*64 + i*16 + l4*4;
    #pragma unroll
    for (int j = 0; j < 4; ++j){
      const int c = colBase + wc*64 + j*16 + l15;
      const float bb = bias ? bias[c] : 0.f;
      #pragma unroll
      for (int jr = 0; jr < 4; ++jr){
        const float v = acc[i][j][jr] + bb;
        const long rr = r0 + jr;
        if (!transposed){
          out[rr * 512 + c] = f2bf(v);
        } else {
          const long m = rr >> 7, s = rr & 127;
          out[(m * 512 + c) * 128 + s] = f2bf(v);
        }
      }
    }
  }
}

// ---- vb97, N=256 tile: VBt[m][n][s] = (mln[m] . Wvb^T)[s][n], BK=64 ------
// 4 col-blocks of 256 per m-panel; acc[4][8]; LDS A 16KB + B 32KB = 48KB.
// grid = dm*4, XCD swizzle keeps panel m on XCD m%8.
__global__ __launch_bounds__(256) void vb97(const unsigned short* __restrict__ A,
                                            const unsigned short* __restrict__ B,
                                            unsigned short* __restrict__ vbt,
                                            int m0){
  __shared__ unsigned short A_lds[8192];    // 2 subtiles x 512 granules
  __shared__ unsigned short B_lds[16384];   // 2 subtiles x 1024 granules
  const int t = threadIdx.x, lane = t & 63, wid = t >> 6;
  const int l15 = lane & 15, l4 = lane >> 4;
  const int wr = wid >> 1, wc = wid & 1;
  const int b = blockIdx.x;
  const int colBase = ((b >> 3) & 3) * 256;
  const long panel = m0 + (b & 7) + 8 * (b >> 5);   // music index m
  const long rowBase = panel * 128;
  f32x4 zero = {0.f,0.f,0.f,0.f};
  f32x4 acc[4][8];
  #pragma unroll
  for (int i = 0; i < 4; ++i)
    #pragma unroll
    for (int j = 0; j < 8; ++j) acc[i][j] = zero;
  for (int ks = 0; ks < 8; ++ks){
    const int k0 = ks * 64;
    #pragma unroll
    for (int sub = 0; sub < 2; ++sub){
      #pragma unroll
      for (int h = 0; h < 2; ++h){
        const int p = h*256 + t;
        const int row = p >> 2, g = (p & 3) ^ ((row >> 1) & 3);
        gload16(A + (rowBase + row)*512 + k0 + sub*32 + g*8, A_lds + sub*4096 + p*8);
      }
      #pragma unroll
      for (int h = 0; h < 4; ++h){
        const int p = h*256 + t;
        const int row = p >> 2, g = (p & 3) ^ ((row >> 1) & 3);
        gload16(B + (long)(colBase + row)*512 + k0 + sub*32 + g*8, B_lds + sub*8192 + p*8);
      }
    }
    __syncthreads();
    #pragma unroll
    for (int sub = 0; sub < 2; ++sub){
      short8 af[4], bfv[8];
      #pragma unroll
      for (int i = 0; i < 4; ++i){
        const int ra = wr*64 + i*16 + l15;
        af[i]  = *(const short8*)(A_lds + sub*4096 + (ra*4 + (l4 ^ ((ra >> 1) & 3)))*8);
      }
      #pragma unroll
      for (int j = 0; j < 8; ++j){
        const int rb = wc*128 + j*16 + l15;
        bfv[j] = *(const short8*)(B_lds + sub*8192 + (rb*4 + (l4 ^ ((rb >> 1) & 3)))*8);
      }
      #pragma unroll
      for (int i = 0; i < 4; ++i)
        #pragma unroll
        for (int j = 0; j < 8; ++j)
          acc[i][j] = mfma16(af[i], bfv[j], acc[i][j]);
    }
    __syncthreads();
  }
  #pragma unroll
  for (int i = 0; i < 4; ++i){
    const int s0 = wr*64 + i*16 + l4*4;
    #pragma unroll
    for (int j = 0; j < 8; ++j){
      const int n = colBase + wc*128 + j*16 + l15;
      #pragma unroll
      for (int jr = 0; jr < 4; ++jr)
        vbt[((long)panel*1024 + n)*128 + s0 + jr] = f2bf(acc[i][j][jr]);
    }
  }
}

// ---- attn_c: per (m, 64-row q block): QK(q2,mln) -> softmax -> W.VBt -> C
// T3-min double-buffered QK (two 8KB k-halves) and PV (two 32KB v-halves);
// w_lds [64][128] granule-XOR swizzled. LDS exactly 81920 B -> 2 blocks/CU.
__global__ __launch_bounds__(256) void attn_c(const unsigned short* __restrict__ q2,
                                              const unsigned short* __restrict__ mlnb,
                                              int m_mln0,
                                              const unsigned short* __restrict__ vbt,
                                              const int* __restrict__ mask,
                                              unsigned short* __restrict__ C,
                                              int m0){
  __shared__ __align__(16) char smem[81920];
  // QK phase: q [0,65536), k halves [65536,73728),[73728,81920)
  unsigned short* q_lin = (unsigned short*)smem;
  unsigned short* k_half0 = (unsigned short*)(smem + 65536);
  unsigned short* k_half1 = (unsigned short*)(smem + 73728);
  // PV phase overlays (q/k dead): w [0,16384), v halves [16384,49152),[49152,81920)
  unsigned short* w_lds = (unsigned short*)smem;
  unsigned short* v_half0 = (unsigned short*)(smem + 16384);
  unsigned short* v_half1 = (unsigned short*)(smem + 49152);
  float* red = (float*)(smem + 49152);   // inside v1; dead before v1 staged
  const int b = blockIdx.x;
  const int m_local = (b & 7) + 8 * (b >> 5);   // bijective for grid = mult of 32
  const int qb = (b >> 3) & 3;
  const int m = m0 + m_local;
  const int t = threadIdx.x, lane = t & 63, wid = t >> 6;
  const int l15 = lane & 15, l4 = lane >> 4;
  // q stage: 64 rows x 64 granules, linear dest, pre-swizzled source
  #pragma unroll
  for (int it = 0; it < 16; ++it){
    const int p = it*256 + t;
    const int row = p >> 6, gp = p & 63;
    const int gsrc = gp ^ (row & 7);
    gload16(q2 + (long)(qb*64 + row)*512 + gsrc*8, q_lin + p*8);
  }
  f32x4 zero = {0.f,0.f,0.f,0.f};
  f32x4 acc[4][2];
  #pragma unroll
  for (int i = 0; i < 4; ++i){ acc[i][0] = zero; acc[i][1] = zero; }
  const unsigned short* kbase = mlnb + (long)(m - m_mln0) * 128 * 512;
  // K stage helper: BK=32 subtile ksub into half h
  #define STAGE_K(ksub, dst)                                                  \
    do {                                                                      \
      _Pragma("unroll")                                                       \
      for (int h2 = 0; h2 < 2; ++h2){                                         \
        const int p = h2*256 + t;                                             \
        const int row = p >> 2, g = (p & 3) ^ ((row >> 1) & 3);               \
        gload16(kbase + (long)row*512 + (ksub)*32 + g*8, (dst) + p*8);        \
      }                                                                       \
    } while (0)
  STAGE_K(0, k_half0);
  for (int ks = 0; ks < 16; ++ks){
    __syncthreads();              // half(ks&1) ready; reads of other half done
    if (ks < 15){
      if (ks & 1){ STAGE_K(ks + 1, k_half0); } else { STAGE_K(ks + 1, k_half1); }
    }
    const unsigned short* kh = (ks & 1) ? k_half1 : k_half0;
    short8 af[4], bfv[2];
    #pragma unroll
    for (int i = 0; i < 4; ++i){
      const int row = i*16 + l15;
      const int gp = (ks*4 + l4) ^ (l15 & 7);
      af[i] = *(const short8*)(q_lin + (row*64 + gp)*8);
    }
    #pragma unroll
    for (int j = 0; j < 2; ++j){
      const int rb = wid*32 + j*16 + l15;
      bfv[j] = *(const short8*)(kh + (rb*4 + (l4 ^ ((rb >> 1) & 3)))*8);
    }
    #pragma unroll
    for (int i = 0; i < 4; ++i)
      #pragma unroll
      for (int j = 0; j < 2; ++j)
        acc[i][j] = mfma16(af[i], bfv[j], acc[i][j]);
  }
  #undef STAGE_K
  __syncthreads();                // all waves done with q_lin/k before overlays
  // ---- in-register wave-parallel softmax (inv folded into weights) ----
  const float scale = 0.04419417382415922f; // 1/sqrt(512)
  const int* mrow = mask + m * 128;
  const int mk0 = mrow[wid*32 + l15];
  const int mk1 = mrow[wid*32 + 16 + l15];
  float e[4][2][4], wmax[4][4];
  #pragma unroll
  for (int i = 0; i < 4; ++i)
    #pragma unroll
    for (int jr = 0; jr < 4; ++jr){
      float v0 = mk0 ? acc[i][0][jr]*scale : -3.0e38f;
      float v1 = mk1 ? acc[i][1][jr]*scale : -3.0e38f;
      float mx = fmaxf(v0, v1);
      mx = fmaxf(mx, __shfl_xor(mx, 1));
      mx = fmaxf(mx, __shfl_xor(mx, 2));
      mx = fmaxf(mx, __shfl_xor(mx, 4));
      mx = fmaxf(mx, __shfl_xor(mx, 8));
      const float e0 = __expf(v0 - mx), e1 = __expf(v1 - mx);
      float sm = e0 + e1;
      sm += __shfl_xor(sm, 1);
      sm += __shfl_xor(sm, 2);
      sm += __shfl_xor(sm, 4);
      sm += __shfl_xor(sm, 8);
      e[i][0][jr] = e0; e[i][1][jr] = e1;
      wmax[i][jr] = mx;
      if (l15 == 0){
        const int r = i*16 + l4*4 + jr;
        red[r*8 + wid*2]     = mx;
        red[r*8 + wid*2 + 1] = sm;
      }
    }
  __syncthreads();                // red visible
  #pragma unroll
  for (int i = 0; i < 4; ++i)
    #pragma unroll
    for (int jr = 0; jr < 4; ++jr){
      const int r = i*16 + l4*4 + jr;
      float4 a = *(const float4*)(red + r*8);
      float4 c = *(const float4*)(red + r*8 + 4);
      const float gm = fmaxf(fmaxf(a.x, a.z), fmaxf(c.x, c.z));
      const float gs = a.y*__expf(a.x - gm) + a.w*__expf(a.z - gm)
                     + c.y*__expf(c.x - gm) + c.w*__expf(c.z - gm);
      const float inv = (gs > 0.f) ? (1.f / gs) : 0.f;
      const float sc = __expf(wmax[i][jr] - gm) * inv;
      #pragma unroll
      for (int j = 0; j < 2; ++j){
        const int cc = wid*32 + j*16 + l15;
        // swizzled store: granule (cc>>3)^(r&7)
        w_lds[r*128 + (((cc >> 3) ^ (r & 7)) << 3) + (cc & 7)] = f2bf(e[i][j][jr] * sc);
      }
    }
  // ---- C part: C[64 x 1024] = W (64x128) . VBt[m] (1024x128)^T, dbuf ----
  const long rowb = (long)m * 256 + qb * 64;
  const unsigned short* vbase = vbt + (long)m * 1024 * 128;
  #define STAGE_V(nb, dst)                                                    \
    do {                                                                      \
      _Pragma("unroll")                                                       \
      for (int it = 0; it < 8; ++it){                                         \
        const int p = it*256 + t;                                             \
        const int row = p >> 4, g = (p & 15) ^ (row & 7);                     \
        gload16(vbase + (long)((nb)*128 + row)*128 + g*8, (dst) + p*8);       \
      }                                                                       \
    } while (0)
  STAGE_V(0, v_half0);            // red already consumed by this thread;
                                  // cross-wave safety from next barrier
  for (int nb = 0; nb < 8; ++nb){
    __syncthreads();              // v half(nb&1) ready; red/w visible (nb=0)
    if (nb < 7){
      if (nb & 1){ STAGE_V(nb + 1, v_half0); } else { STAGE_V(nb + 1, v_half1); }
    }
    const unsigned short* vh = (nb & 1) ? v_half1 : v_half0;
    f32x4 pacc[4][2];
    #pragma unroll
    for (int i = 0; i < 4; ++i){ pacc[i][0] = zero; pacc[i][1] = zero; }
    #pragma unroll
    for (int ks2 = 0; ks2 < 4; ++ks2){
      short8 wf[4], vf[2];
      #pragma unroll
      for (int i = 0; i < 4; ++i){
        const int row = i*16 + l15;
        const int gsw = (ks2*4 + l4) ^ (row & 7);
        wf[i] = *(const short8*)(w_lds + row*128 + gsw*8);
      }
      #pragma unroll
      for (int j = 0; j < 2; ++j){
        const int rv = wid*32 + j*16 + l15;
        vf[j] = *(const short8*)(vh + (rv*16 + ((ks2*4 + l4) ^ (rv & 7)))*8);
      }
      #pragma unroll
      for (int i = 0; i < 4; ++i)
        #pragma unroll
        for (int j = 0; j < 2; ++j)
          pacc[i][j] = mfma16(wf[i], vf[j], pacc[i][j]);
    }
    #pragma unroll
    for (int i = 0; i < 4; ++i)
      #pragma unroll
      for (int j = 0; j < 2; ++j)
        #pragma unroll
        for (int jr = 0; jr < 4; ++jr)
          C[(rowb + i*16 + l4*4 + jr) * 1024 + nb*128 + wid*32 + j*16 + l15] =
              f2bf(pacc[i][j][jr]);
  }
  #undef STAGE_V
}

// ---- LN epilogue, one wave per row, IN-PLACE in d_out --------------------
__global__ __launch_bounds__(256) void ln_epilogue(
    const unsigned short* Cb, float* out,   // SAME buffer; no __restrict__
    const float* __restrict__ bias_cat, const float* __restrict__ u,
    const float* __restrict__ v,
    const float* __restrict__ g2, const float* __restrict__ b2,
    const float* __restrict__ g3, const float* __restrict__ b3){
  const int wid = threadIdx.x >> 6, lane = threadIdx.x & 63;
  const long row = (long)blockIdx.x * 4 + wid;
  const unsigned short* cr = Cb + row * 1024;
  short8 ov = *(const short8*)(cr + lane * 8);
  short8 pv = *(const short8*)(cr + 512 + lane * 8);
  const int n0 = lane * 8;
  float4 bo0 = *(const float4*)(bias_cat + n0);
  float4 bo1 = *(const float4*)(bias_cat + n0 + 4);
  float4 c20 = *(const float4*)(bias_cat + 512 + n0);
  float4 c21 = *(const float4*)(bias_cat + 512 + n0 + 4);
  float o[8], p[8];
  #pragma unroll
  for (int j = 0; j < 4; ++j){
    o[j]   = bf2f((unsigned short)ov[j])   + ((const float*)&bo0)[j];
    o[4+j] = bf2f((unsigned short)ov[4+j]) + ((const float*)&bo1)[j];
    p[j]   = bf2f((unsigned short)pv[j])   + ((const float*)&c20)[j];
    p[4+j] = bf2f((unsigned short)pv[4+j]) + ((const float*)&c21)[j];
  }
  float s = 0.f, s2 = 0.f;
  #pragma unroll
  for (int j = 0; j < 8; ++j){ s += o[j]; s2 += o[j]*o[j]; }
  #pragma unroll
  for (int m = 1; m < 64; m <<= 1){ s += __shfl_xor(s, m); s2 += __shfl_xor(s2, m); }
  const float mu2 = s * (1.f/512.f);
  const float rstd2 = rsqrtf(s2 * (1.f/512.f) - mu2*mu2 + 1e-5f);
  float4 uv0 = *(const float4*)(u + n0), uv1 = *(const float4*)(u + n0 + 4);
  float4 vv0 = *(const float4*)(v + n0), vv1 = *(const float4*)(v + n0 + 4);
  float4 g20v = *(const float4*)(g2 + n0), g21v = *(const float4*)(g2 + n0 + 4);
  float4 b20v = *(const float4*)(b2 + n0), b21v = *(const float4*)(b2 + n0 + 4);
  float y[8];
  #pragma unroll
  for (int j = 0; j < 4; ++j){
    const float lin0 = rstd2 * (p[j]   - mu2 * ((const float*)&uv0)[j]) + ((const float*)&vv0)[j];
    const float lin1 = rstd2 * (p[4+j] - mu2 * ((const float*)&uv1)[j]) + ((const float*)&vv1)[j];
    const float oln0 = (o[j]   - mu2) * rstd2 * ((const float*)&g20v)[j] + ((const float*)&b20v)[j];
    const float oln1 = (o[4+j] - mu2) * rstd2 * ((const float*)&g21v)[j] + ((const float*)&b21v)[j];
    y[j]   = oln0 + lin0;
    y[4+j] = oln1 + lin1;
  }
  float t1 = 0.f, t2 = 0.f;
  #pragma unroll
  for (int j = 0; j < 8; ++j){ t1 += y[j]; t2 += y[j]*y[j]; }
  #pragma unroll
  for (int m = 1; m < 64; m <<= 1){ t1 += __shfl_xor(t1, m); t2 += __shfl_xor(t2, m); }
  const float mu3 = t1 * (1.f/512.f);
  const float rstd3 = rsqrtf(t2 * (1.f/512.f) - mu3*mu3 + 1e-5f);
  float4 g30v = *(const float4*)(g3 + n0), g31v = *(const float4*)(g3 + n0 + 4);
  float4 b30v = *(const float4*)(b3 + n0), b31v = *(const float4*)(b3 + n0 + 4);
  float4 r0, r1;
  #pragma unroll
  for (int j = 0; j < 4; ++j){
    ((float*)&r0)[j] = (y[j]   - mu3) * rstd3 * ((const float*)&g30v)[j] + ((const float*)&b30v)[j];
    ((float*)&r1)[j] = (y[4+j] - mu3) * rstd3 * ((const float*)&g31v)[j] + ((const float*)&b31v)[j];
  }
  *(float4*)(out + row * 512 + n0)     = r0;
  *(float4*)(out + row * 512 + n0 + 4) = r1;
}

extern "C" void kernel_launch(void* const* d_in, const int* in_sizes, int n_in,
                              void* d_out, int out_size, void* d_ws, size_t ws_size,
                              hipStream_t stream){
  const float* video = (const float*)d_in[0];
  const float* music = (const float*)d_in[1];
  const int*   mask  = (const int*)d_in[2];
  const float* ln1g  = (const float*)d_in[3];
  const float* ln1b  = (const float*)d_in[4];
  const float* Wq = (const float*)d_in[5];  const float* bq = (const float*)d_in[6];
  const float* Wk = (const float*)d_in[7];
  const float* Wv = (const float*)d_in[9];  const float* bv = (const float*)d_in[10];
  const float* Wo = (const float*)d_in[11]; const float* bo = (const float*)d_in[12];
  const float* Wl = (const float*)d_in[13]; const float* bl = (const float*)d_in[14];
  const float* g2 = (const float*)d_in[15]; const float* b2 = (const float*)d_in[16];
  const float* g3 = (const float*)d_in[17]; const float* b3 = (const float*)d_in[18];

  // d_out: mln at top [192M,256M); C/out occupy [0,256M) written ascending so
  // every chunk's writes stay strictly below all not-yet-consumed mln bytes.
  char* ob = (char*)d_out;
  unsigned short* mln  = (unsigned short*)(ob + 201326592);     // [65536][512] bf16
  unsigned short* Cb   = (unsigned short*)ob;                   // [131072][1024] bf16
  float* outp = (float*)d_out;

  char* wsb = (char*)d_ws;
  unsigned short* vbt    = (unsigned short*)wsb;                // [512][1024][128] bf16 (134MB)
  unsigned short* Wq_bf  = (unsigned short*)(wsb + 134217728);
  unsigned short* Bcat   = Wq_bf + 262144;                      // [1024][512]: Wo ; W2
  unsigned short* wlp    = Bcat + 524288;
  unsigned short* WoT    = wlp + 262144;
  unsigned short* WkT    = WoT + 262144;
  unsigned short* WvT    = WkT + 262144;
  unsigned short* Wvb    = WvT + 262144;                        // [1024][512]
  unsigned short* q_ws   = Wvb + 524288;                        // [256][512]
  unsigned short* q2_ws  = q_ws + 131072;                       // [256][512]
  unsigned short* vln    = q2_ws + 131072;                      // [256][512]
  unsigned short* mln_cp = vln + 131072;                        // [8*128][512] tail copy
  float* bias_cat = (float*)(mln_cp + 524288);                  // [1024]
  float* u_vec    = bias_cat + 1024;                            // [512]
  float* v_vec    = u_vec + 512;                                // [512]

  // ---- weight prep ----
  cvt2_f32_bf16<<<512, 256, 0, stream>>>(Wq, Wq_bf, Wo, Bcat);  // Bcat rows 0..511 = Wo
  ln_weight_prep<<<128, 256, 0, stream>>>(Wl, g2, b2, bl, bo, wlp, u_vec, v_vec, bias_cat);
  transpose3_bf<<<dim3(8, 8, 3), 256, 0, stream>>>(Wo, WoT, Wk, WkT, Wv, WvT);
  gemm_bt<<<dim3(4, 4), 256, 0, stream>>>(wlp, WoT, nullptr, Bcat + 262144, 0); // W2
  gemm_bt<<<dim3(4, 8), 256, 0, stream>>>(Bcat, WvT, nullptr, Wvb, 0);          // Wvb = Bcat*Wv
  cvb_add<<<256, 256, 0, stream>>>(Bcat, bv, bias_cat);

  // ---- activations ----
  ln_rows<<<16384, 256, 0, stream>>>(music, ln1g, ln1b, mln, 65536);
  ln_rows<<<64,    256, 0, stream>>>(video, ln1g, ln1b, vln, 256);
  gemm_bt<<<dim3(4, 2), 256, 0, stream>>>(vln, Wq_bf, bq, q_ws, 0);      // q
  gemm_bt<<<dim3(4, 2), 256, 0, stream>>>(q_ws, WkT, nullptr, q2_ws, 0); // q2 = q*Wk

  // ---- chunk-interleaved producer-consumer: vb97 chunk -> attn_c -> LN.
  const int vm0[5] = {0, 128, 256, 384, 480};
  const int vdm[5] = {128, 128, 128, 96, 32};   // vb97 covers all 512 m
  const int am0[5] = {0, 128, 256, 384, 480};
  const int adm[5] = {128, 128, 128, 96, 24};   // attn stops at 504 (tail below)
  for (int cidx = 0; cidx < 5; ++cidx){
    vb97<<<vdm[cidx] * 4, 256, 0, stream>>>(mln, Wvb, vbt, vm0[cidx]);
    const int m0 = am0[cidx], dm = adm[cidx];
    attn_c<<<dm * 4, 256, 0, stream>>>(q2_ws, mln, 0, vbt, mask, Cb, m0);
    ln_epilogue<<<dm * 64, 256, 0, stream>>>(Cb + (long)m0*256*1024,
                                             outp + (long)m0*256*512,
                                             bias_cat, u_vec, v_vec, g2, b2, g3, b3);
  }
  // tail m=504..511: its C writes overlap mln[480..512) -> use a copy
  copy_bf<<<256, 256, 0, stream>>>(mln + (long)504*128*512, mln_cp);
  attn_c<<<32, 256, 0, stream>>>(q2_ws, mln_cp, 504, vbt, mask, Cb, 504);
  ln_epilogue<<<512, 256, 0, stream>>>(Cb + (long)504*256*1024,
                                       outp + (long)504*256*512,
                                       bias_cat, u_vec, v_vec, g2, b2, g3, b3);
}

// Round 17
// 585.439 us; speedup vs baseline: 1.0495x; 1.0495x over previous
//
#include <hip/hip_runtime.h>

typedef __attribute__((ext_vector_type(8))) short short8;
typedef __attribute__((ext_vector_type(4))) float f32x4;
typedef __attribute__((ext_vector_type(4))) unsigned short u16x4;

__device__ __forceinline__ unsigned short f2bf(float f){
  unsigned int u = __builtin_bit_cast(unsigned int, f);
  u = (u + 0x7FFFu + ((u >> 16) & 1u)) >> 16;
  return (unsigned short)u;
}
__device__ __forceinline__ float bf2f(unsigned short h){
  unsigned int u = ((unsigned int)h) << 16;
  return __builtin_bit_cast(float, u);
}
__device__ __forceinline__ f32x4 mfma16(short8 a, short8 b, f32x4 c){
  return __builtin_amdgcn_mfma_f32_16x16x32_bf16(a, b, c, 0, 0, 0);
}
// async global->LDS, 16B/lane; lds base wave-uniform (HW: base + lane*16)
__device__ __forceinline__ void gload16(const void* g, void* l){
  __builtin_amdgcn_global_load_lds((const __attribute__((address_space(1))) void*)g,
                                   (__attribute__((address_space(3))) void*)l, 16, 0, 0);
}

// ---------------- f32 -> bf16 conversion, two 512x512 matrices ------------
__global__ __launch_bounds__(256) void cvt2_f32_bf16(const float* __restrict__ s0,
                                                     unsigned short* __restrict__ d0,
                                                     const float* __restrict__ s1,
                                                     unsigned short* __restrict__ d1){
  const int half = blockIdx.x >> 8;
  const float* src = half ? s1 : s0;
  unsigned short* dst = half ? d1 : d0;
  int i = ((blockIdx.x & 255) * 256 + threadIdx.x) * 4;
  float4 v = *(const float4*)(src + i);
  u16x4 o = { f2bf(v.x), f2bf(v.y), f2bf(v.z), f2bf(v.w) };
  *(u16x4*)(dst + i) = o;
}

// ---------------- bf16 copy (524288 elems) --------------------------------
__global__ __launch_bounds__(256) void copy_bf(const unsigned short* __restrict__ src,
                                               unsigned short* __restrict__ dst){
  int i = (blockIdx.x * 256 + threadIdx.x) * 8;
  *(short8*)(dst + i) = *(const short8*)(src + i);
}

// ---------------- LayerNorm over D=512, one wave per row, bf16 out --------
__global__ __launch_bounds__(256) void ln_rows(const float* __restrict__ x,
                                               const float* __restrict__ g,
                                               const float* __restrict__ b,
                                               unsigned short* __restrict__ y,
                                               int nrows){
  const int wid = threadIdx.x >> 6, lane = threadIdx.x & 63;
  const int row = blockIdx.x * 4 + wid;
  if (row >= nrows) return;
  const float* xr = x + (long)row * 512;
  float4 v0 = *(const float4*)(xr + lane * 4);
  float4 v1 = *(const float4*)(xr + 256 + lane * 4);
  float s  = v0.x + v0.y + v0.z + v0.w + v1.x + v1.y + v1.z + v1.w;
  float s2 = v0.x*v0.x + v0.y*v0.y + v0.z*v0.z + v0.w*v0.w
           + v1.x*v1.x + v1.y*v1.y + v1.z*v1.z + v1.w*v1.w;
  #pragma unroll
  for (int m = 1; m < 64; m <<= 1){ s += __shfl_xor(s, m); s2 += __shfl_xor(s2, m); }
  const float mu = s * (1.f/512.f);
  const float rstd = rsqrtf(s2 * (1.f/512.f) - mu*mu + 1e-5f);
  float4 g0 = *(const float4*)(g + lane*4), g1 = *(const float4*)(g + 256 + lane*4);
  float4 b0 = *(const float4*)(b + lane*4), b1 = *(const float4*)(b + 256 + lane*4);
  u16x4 o0 = { f2bf((v0.x-mu)*rstd*g0.x + b0.x), f2bf((v0.y-mu)*rstd*g0.y + b0.y),
               f2bf((v0.z-mu)*rstd*g0.z + b0.z), f2bf((v0.w-mu)*rstd*g0.w + b0.w) };
  u16x4 o1 = { f2bf((v1.x-mu)*rstd*g1.x + b1.x), f2bf((v1.y-mu)*rstd*g1.y + b1.y),
               f2bf((v1.z-mu)*rstd*g1.z + b1.z), f2bf((v1.w-mu)*rstd*g1.w + b1.w) };
  *(u16x4*)(y + (long)row * 512 + lane * 4) = o0;
  *(u16x4*)(y + (long)row * 512 + 256 + lane * 4) = o1;
}

// ---- prep: Wl'[n][c]=Wl[n][c]*g2[c] (bf16); u[n]=sum Wl'; v[n]=Wl.b2+bl;
//      bias_cat[n]=bo[n]; bias_cat[512+n]=c2[n]=sum Wl'[n][c]*bo[c] ---------
__global__ __launch_bounds__(256) void ln_weight_prep(
    const float* __restrict__ Wl, const float* __restrict__ g2,
    const float* __restrict__ b2, const float* __restrict__ bl,
    const float* __restrict__ bo,
    unsigned short* __restrict__ wlp, float* __restrict__ u,
    float* __restrict__ v, float* __restrict__ bias_cat){
  const int wid = threadIdx.x >> 6, lane = threadIdx.x & 63;
  const int n = blockIdx.x * 4 + wid;
  const float* row = Wl + (long)n * 512;
  float su = 0.f, sv = 0.f, sc = 0.f;
  #pragma unroll
  for (int h = 0; h < 2; ++h){
    const int c0 = h * 256 + lane * 4;
    float4 w  = *(const float4*)(row + c0);
    float4 gg = *(const float4*)(g2 + c0);
    float4 bb = *(const float4*)(b2 + c0);
    float4 oo = *(const float4*)(bo + c0);
    float4 wp = { w.x*gg.x, w.y*gg.y, w.z*gg.z, w.w*gg.w };
    su += wp.x + wp.y + wp.z + wp.w;
    sv += w.x*bb.x + w.y*bb.y + w.z*bb.z + w.w*bb.w;
    sc += wp.x*oo.x + wp.y*oo.y + wp.z*oo.z + wp.w*oo.w;
    u16x4 o = { f2bf(wp.x), f2bf(wp.y), f2bf(wp.z), f2bf(wp.w) };
    *(u16x4*)(wlp + (long)n * 512 + c0) = o;
  }
  #pragma unroll
  for (int m = 1; m < 64; m <<= 1){
    su += __shfl_xor(su, m); sv += __shfl_xor(sv, m); sc += __shfl_xor(sc, m);
  }
  if (lane == 0){
    u[n] = su;
    v[n] = sv + bl[n];
    bias_cat[n] = bo[n];
    bias_cat[512 + n] = sc;
  }
}

// ---- cvb: bias_cat[n] += dot(Bcat[n] (bf16,512), bv) ---------------------
__global__ __launch_bounds__(256) void cvb_add(const unsigned short* __restrict__ Bc,
                                               const float* __restrict__ bv,
                                               float* __restrict__ bias_cat){
  const int wid = threadIdx.x >> 6, lane = threadIdx.x & 63;
  const int n = blockIdx.x * 4 + wid;   // 0..1023
  const unsigned short* row = Bc + (long)n * 512;
  short8 a = *(const short8*)(row + lane * 8);
  float s = 0.f;
  #pragma unroll
  for (int j = 0; j < 8; ++j) s += bf2f((unsigned short)a[j]) * bv[lane*8 + j];
  #pragma unroll
  for (int m = 1; m < 64; m <<= 1) s += __shfl_xor(s, m);
  if (lane == 0) bias_cat[n] += s;
}

// ---- transpose three 512x512: dst[k][c] = bf16(src[c][k]) ----------------
__global__ __launch_bounds__(256) void transpose3_bf(
    const float* __restrict__ s0, unsigned short* __restrict__ d0,
    const float* __restrict__ s1, unsigned short* __restrict__ d1,
    const float* __restrict__ s2, unsigned short* __restrict__ d2){
  __shared__ float tile[64][65];
  const float* src = (blockIdx.z == 0) ? s0 : (blockIdx.z == 1) ? s1 : s2;
  unsigned short* dst = (blockIdx.z == 0) ? d0 : (blockIdx.z == 1) ? d1 : d2;
  const int t = threadIdx.x;
  const int k0 = blockIdx.x * 64, c0 = blockIdx.y * 64;
  const int j = t & 63, i = t >> 6;
  #pragma unroll
  for (int rr = 0; rr < 16; ++rr)
    tile[i + rr*4][j] = src[(long)(c0 + i + rr*4) * 512 + k0 + j];
  __syncthreads();
  #pragma unroll
  for (int rr = 0; rr < 16; ++rr)
    dst[(long)(k0 + i + rr*4) * 512 + c0 + j] = f2bf(tile[j][i + rr*4]);
}

// ---------------- C = A(rows x 512) * B(512 x 512)^T + bias ---------------
__global__ __launch_bounds__(256) void gemm_bt(const unsigned short* __restrict__ A,
                                               const unsigned short* __restrict__ B,
                                               const float* __restrict__ bias,
                                               unsigned short* __restrict__ out,
                                               int transposed){
  __shared__ unsigned short At[128][40];
  __shared__ unsigned short Bt[128][40];
  const int t = threadIdx.x, lane = t & 63, wid = t >> 6;
  const int l15 = lane & 15, l4 = lane >> 4;
  const int wr = wid >> 1, wc = wid & 1;
  const int rowBase = blockIdx.y * 128;
  const int colBase = blockIdx.x * 128;
  f32x4 zero = {0.f, 0.f, 0.f, 0.f};
  f32x4 acc[4][4];
  #pragma unroll
  for (int i = 0; i < 4; ++i)
    #pragma unroll
    for (int j = 0; j < 4; ++j) acc[i][j] = zero;
  const int sr = t >> 1, sh = (t & 1) * 16;
  for (int ks = 0; ks < 16; ++ks){
    const int k0 = ks * 32;
    const unsigned short* sa = A + (long)(rowBase + sr) * 512 + k0 + sh;
    *(short8*)&At[sr][sh]     = *(const short8*)sa;
    *(short8*)&At[sr][sh + 8] = *(const short8*)(sa + 8);
    const unsigned short* sb = B + (long)(colBase + sr) * 512 + k0 + sh;
    *(short8*)&Bt[sr][sh]     = *(const short8*)sb;
    *(short8*)&Bt[sr][sh + 8] = *(const short8*)(sb + 8);
    __syncthreads();
    short8 af[4], bfv[4];
    #pragma unroll
    for (int i = 0; i < 4; ++i) af[i]  = *(const short8*)&At[wr*64 + i*16 + l15][l4*8];
    #pragma unroll
    for (int i = 0; i < 4; ++i) bfv[i] = *(const short8*)&Bt[wc*64 + i*16 + l15][l4*8];
    #pragma unroll
    for (int i = 0; i < 4; ++i)
      #pragma unroll
      for (int j = 0; j < 4; ++j)
        acc[i][j] = mfma16(af[i], bfv[j], acc[i][j]);
    __syncthreads();
  }
  #pragma unroll
  for (int i = 0; i < 4; ++i){
    const int r0 = rowBase + wr*64 + i*16 + l4*4;
    #pragma unroll
    for (int j = 0; j < 4; ++j){
      const int c = colBase + wc*64 + j*16 + l15;
      const float bb = bias ? bias[c] : 0.f;
      #pragma unroll
      for (int jr = 0; jr < 4; ++jr){
        const float v = acc[i][j][jr] + bb;
        const long rr = r0 + jr;
        if (!transposed){
          out[rr * 512 + c] = f2bf(v);
        } else {
          const long m = rr >> 7, s = rr & 127;
          out[(m * 512 + c) * 128 + s] = f2bf(v);
        }
      }
    }
  }
}

// ---- vb97 chunk: VBt[m][n][s] = (mln[m] . Wvb^T)[s][n], BK=64, m in
// [m0, m0+dm) where grid = dm*8; XCD swizzle keeps panel m on XCD m%8.
__global__ __launch_bounds__(256) void vb97(const unsigned short* __restrict__ A,
                                            const unsigned short* __restrict__ B,
                                            unsigned short* __restrict__ vbt,
                                            int m0){
  __shared__ unsigned short A_lds[8192];
  __shared__ unsigned short B_lds[8192];
  const int t = threadIdx.x, lane = t & 63, wid = t >> 6;
  const int l15 = lane & 15, l4 = lane >> 4;
  const int wr = wid >> 1, wc = wid & 1;
  const int b = blockIdx.x;
  const int kk = b >> 3;
  const int colBase = (kk & 7) * 128;
  const long panel = m0 + (b & 7) + 8 * (kk >> 3);   // music index m
  const long rowBase = panel * 128;
  f32x4 zero = {0.f,0.f,0.f,0.f};
  f32x4 acc[4][4];
  #pragma unroll
  for (int i = 0; i < 4; ++i)
    #pragma unroll
    for (int j = 0; j < 4; ++j) acc[i][j] = zero;
  for (int ks = 0; ks < 8; ++ks){
    const int k0 = ks * 64;
    #pragma unroll
    for (int sub = 0; sub < 2; ++sub){
      #pragma unroll
      for (int h = 0; h < 2; ++h){
        const int p = h*256 + t;
        const int row = p >> 2, g = (p & 3) ^ ((row >> 1) & 3);
        gload16(A + (rowBase + row)*512 + k0 + sub*32 + g*8, A_lds + sub*4096 + p*8);
        gload16(B + (long)(colBase + row)*512 + k0 + sub*32 + g*8, B_lds + sub*4096 + p*8);
      }
    }
    __syncthreads();
    #pragma unroll
    for (int sub = 0; sub < 2; ++sub){
      short8 af[4], bfv[4];
      #pragma unroll
      for (int i = 0; i < 4; ++i){
        const int ra = wr*64 + i*16 + l15;
        af[i]  = *(const short8*)(A_lds + sub*4096 + (ra*4 + (l4 ^ ((ra >> 1) & 3)))*8);
        const int rb = wc*64 + i*16 + l15;
        bfv[i] = *(const short8*)(B_lds + sub*4096 + (rb*4 + (l4 ^ ((rb >> 1) & 3)))*8);
      }
      #pragma unroll
      for (int i = 0; i < 4; ++i)
        #pragma unroll
        for (int j = 0; j < 4; ++j)
          acc[i][j] = mfma16(af[i], bfv[j], acc[i][j]);
    }
    __syncthreads();
  }
  #pragma unroll
  for (int i = 0; i < 4; ++i){
    const int s0 = wr*64 + i*16 + l4*4;
    #pragma unroll
    for (int j = 0; j < 4; ++j){
      const int n = colBase + wc*64 + j*16 + l15;
      #pragma unroll
      for (int jr = 0; jr < 4; ++jr)
        vbt[((long)panel*1024 + n)*128 + s0 + jr] = f2bf(acc[i][j][jr]);
    }
  }
}

// ---- attn_c: per (m, 64-row q block): QK(q2,mln) -> softmax -> W.VBt -> C
// T3-min double-buffered QK (two 8KB k-halves) and PV (two 32KB v-halves);
// w_lds [64][128] granule-XOR swizzled. LDS exactly 81920 B -> 2 blocks/CU.
__global__ __launch_bounds__(256) void attn_c(const unsigned short* __restrict__ q2,
                                              const unsigned short* __restrict__ mlnb,
                                              int m_mln0,
                                              const unsigned short* __restrict__ vbt,
                                              const int* __restrict__ mask,
                                              unsigned short* __restrict__ C,
                                              int m0){
  __shared__ __align__(16) char smem[81920];
  // QK phase: q [0,65536), k halves [65536,73728),[73728,81920)
  unsigned short* q_lin = (unsigned short*)smem;
  unsigned short* k_half0 = (unsigned short*)(smem + 65536);
  unsigned short* k_half1 = (unsigned short*)(smem + 73728);
  // PV phase overlays (q/k dead): w [0,16384), v halves [16384,49152),[49152,81920)
  unsigned short* w_lds = (unsigned short*)smem;
  unsigned short* v_half0 = (unsigned short*)(smem + 16384);
  unsigned short* v_half1 = (unsigned short*)(smem + 49152);
  float* red = (float*)(smem + 49152);   // inside v1; dead before v1 staged
  const int b = blockIdx.x;
  const int m_local = (b & 7) + 8 * (b >> 5);   // bijective for grid = mult of 32
  const int qb = (b >> 3) & 3;
  const int m = m0 + m_local;
  const int t = threadIdx.x, lane = t & 63, wid = t >> 6;
  const int l15 = lane & 15, l4 = lane >> 4;
  // q stage: 64 rows x 64 granules, linear dest, pre-swizzled source
  #pragma unroll
  for (int it = 0; it < 16; ++it){
    const int p = it*256 + t;
    const int row = p >> 6, gp = p & 63;
    const int gsrc = gp ^ (row & 7);
    gload16(q2 + (long)(qb*64 + row)*512 + gsrc*8, q_lin + p*8);
  }
  f32x4 zero = {0.f,0.f,0.f,0.f};
  f32x4 acc[4][2];
  #pragma unroll
  for (int i = 0; i < 4; ++i){ acc[i][0] = zero; acc[i][1] = zero; }
  const unsigned short* kbase = mlnb + (long)(m - m_mln0) * 128 * 512;
  // K stage helper: BK=32 subtile ksub into half h
  #define STAGE_K(ksub, dst)                                                  \
    do {                                                                      \
      _Pragma("unroll")                                                       \
      for (int h2 = 0; h2 < 2; ++h2){                                         \
        const int p = h2*256 + t;                                             \
        const int row = p >> 2, g = (p & 3) ^ ((row >> 1) & 3);               \
        gload16(kbase + (long)row*512 + (ksub)*32 + g*8, (dst) + p*8);        \
      }                                                                       \
    } while (0)
  STAGE_K(0, k_half0);
  for (int ks = 0; ks < 16; ++ks){
    __syncthreads();              // half(ks&1) ready; reads of other half done
    if (ks < 15){
      if (ks & 1){ STAGE_K(ks + 1, k_half0); } else { STAGE_K(ks + 1, k_half1); }
    }
    const unsigned short* kh = (ks & 1) ? k_half1 : k_half0;
    short8 af[4], bfv[2];
    #pragma unroll
    for (int i = 0; i < 4; ++i){
      const int row = i*16 + l15;
      const int gp = (ks*4 + l4) ^ (l15 & 7);
      af[i] = *(const short8*)(q_lin + (row*64 + gp)*8);
    }
    #pragma unroll
    for (int j = 0; j < 2; ++j){
      const int rb = wid*32 + j*16 + l15;
      bfv[j] = *(const short8*)(kh + (rb*4 + (l4 ^ ((rb >> 1) & 3)))*8);
    }
    #pragma unroll
    for (int i = 0; i < 4; ++i)
      #pragma unroll
      for (int j = 0; j < 2; ++j)
        acc[i][j] = mfma16(af[i], bfv[j], acc[i][j]);
  }
  #undef STAGE_K
  __syncthreads();                // all waves done with q_lin/k before overlays
  // ---- in-register wave-parallel softmax (inv folded into weights) ----
  const float scale = 0.04419417382415922f; // 1/sqrt(512)
  const int* mrow = mask + m * 128;
  const int mk0 = mrow[wid*32 + l15];
  const int mk1 = mrow[wid*32 + 16 + l15];
  float e[4][2][4], wmax[4][4];
  #pragma unroll
  for (int i = 0; i < 4; ++i)
    #pragma unroll
    for (int jr = 0; jr < 4; ++jr){
      float v0 = mk0 ? acc[i][0][jr]*scale : -3.0e38f;
      float v1 = mk1 ? acc[i][1][jr]*scale : -3.0e38f;
      float mx = fmaxf(v0, v1);
      mx = fmaxf(mx, __shfl_xor(mx, 1));
      mx = fmaxf(mx, __shfl_xor(mx, 2));
      mx = fmaxf(mx, __shfl_xor(mx, 4));
      mx = fmaxf(mx, __shfl_xor(mx, 8));
      const float e0 = __expf(v0 - mx), e1 = __expf(v1 - mx);
      float sm = e0 + e1;
      sm += __shfl_xor(sm, 1);
      sm += __shfl_xor(sm, 2);
      sm += __shfl_xor(sm, 4);
      sm += __shfl_xor(sm, 8);
      e[i][0][jr] = e0; e[i][1][jr] = e1;
      wmax[i][jr] = mx;
      if (l15 == 0){
        const int r = i*16 + l4*4 + jr;
        red[r*8 + wid*2]     = mx;
        red[r*8 + wid*2 + 1] = sm;
      }
    }
  __syncthreads();                // red visible
  #pragma unroll
  for (int i = 0; i < 4; ++i)
    #pragma unroll
    for (int jr = 0; jr < 4; ++jr){
      const int r = i*16 + l4*4 + jr;
      float4 a = *(const float4*)(red + r*8);
      float4 c = *(const float4*)(red + r*8 + 4);
      const float gm = fmaxf(fmaxf(a.x, a.z), fmaxf(c.x, c.z));
      const float gs = a.y*__expf(a.x - gm) + a.w*__expf(a.z - gm)
                     + c.y*__expf(c.x - gm) + c.w*__expf(c.z - gm);
      const float inv = (gs > 0.f) ? (1.f / gs) : 0.f;
      const float sc = __expf(wmax[i][jr] - gm) * inv;
      #pragma unroll
      for (int j = 0; j < 2; ++j){
        const int cc = wid*32 + j*16 + l15;
        // swizzled store: granule (cc>>3)^(r&7)
        w_lds[r*128 + (((cc >> 3) ^ (r & 7)) << 3) + (cc & 7)] = f2bf(e[i][j][jr] * sc);
      }
    }
  // ---- C part: C[64 x 1024] = W (64x128) . VBt[m] (1024x128)^T, dbuf ----
  const long rowb = (long)m * 256 + qb * 64;
  const unsigned short* vbase = vbt + (long)m * 1024 * 128;
  #define STAGE_V(nb, dst)                                                    \
    do {                                                                      \
      _Pragma("unroll")                                                       \
      for (int it = 0; it < 8; ++it){                                         \
        const int p = it*256 + t;                                             \
        const int row = p >> 4, g = (p & 15) ^ (row & 7);                     \
        gload16(vbase + (long)((nb)*128 + row)*128 + g*8, (dst) + p*8);       \
      }                                                                       \
    } while (0)
  STAGE_V(0, v_half0);            // red already consumed by this thread;
                                  // cross-wave safety from next barrier
  for (int nb = 0; nb < 8; ++nb){
    __syncthreads();              // v half(nb&1) ready; red/w visible (nb=0)
    if (nb < 7){
      if (nb & 1){ STAGE_V(nb + 1, v_half0); } else { STAGE_V(nb + 1, v_half1); }
    }
    const unsigned short* vh = (nb & 1) ? v_half1 : v_half0;
    f32x4 pacc[4][2];
    #pragma unroll
    for (int i = 0; i < 4; ++i){ pacc[i][0] = zero; pacc[i][1] = zero; }
    #pragma unroll
    for (int ks2 = 0; ks2 < 4; ++ks2){
      short8 wf[4], vf[2];
      #pragma unroll
      for (int i = 0; i < 4; ++i){
        const int row = i*16 + l15;
        const int gsw = (ks2*4 + l4) ^ (row & 7);
        wf[i] = *(const short8*)(w_lds + row*128 + gsw*8);
      }
      #pragma unroll
      for (int j = 0; j < 2; ++j){
        const int rv = wid*32 + j*16 + l15;
        vf[j] = *(const short8*)(vh + (rv*16 + ((ks2*4 + l4) ^ (rv & 7)))*8);
      }
      #pragma unroll
      for (int i = 0; i < 4; ++i)
        #pragma unroll
        for (int j = 0; j < 2; ++j)
          pacc[i][j] = mfma16(wf[i], vf[j], pacc[i][j]);
    }
    #pragma unroll
    for (int i = 0; i < 4; ++i)
      #pragma unroll
      for (int j = 0; j < 2; ++j)
        #pragma unroll
        for (int jr = 0; jr < 4; ++jr)
          C[(rowb + i*16 + l4*4 + jr) * 1024 + nb*128 + wid*32 + j*16 + l15] =
              f2bf(pacc[i][j][jr]);
  }
  #undef STAGE_V
}

// ---- LN epilogue, one wave per row, IN-PLACE in d_out --------------------
__global__ __launch_bounds__(256) void ln_epilogue(
    const unsigned short* Cb, float* out,   // SAME buffer; no __restrict__
    const float* __restrict__ bias_cat, const float* __restrict__ u,
    const float* __restrict__ v,
    const float* __restrict__ g2, const float* __restrict__ b2,
    const float* __restrict__ g3, const float* __restrict__ b3){
  const int wid = threadIdx.x >> 6, lane = threadIdx.x & 63;
  const long row = (long)blockIdx.x * 4 + wid;
  const unsigned short* cr = Cb + row * 1024;
  short8 ov = *(const short8*)(cr + lane * 8);
  short8 pv = *(const short8*)(cr + 512 + lane * 8);
  const int n0 = lane * 8;
  float4 bo0 = *(const float4*)(bias_cat + n0);
  float4 bo1 = *(const float4*)(bias_cat + n0 + 4);
  float4 c20 = *(const float4*)(bias_cat + 512 + n0);
  float4 c21 = *(const float4*)(bias_cat + 512 + n0 + 4);
  float o[8], p[8];
  #pragma unroll
  for (int j = 0; j < 4; ++j){
    o[j]   = bf2f((unsigned short)ov[j])   + ((const float*)&bo0)[j];
    o[4+j] = bf2f((unsigned short)ov[4+j]) + ((const float*)&bo1)[j];
    p[j]   = bf2f((unsigned short)pv[j])   + ((const float*)&c20)[j];
    p[4+j] = bf2f((unsigned short)pv[4+j]) + ((const float*)&c21)[j];
  }
  float s = 0.f, s2 = 0.f;
  #pragma unroll
  for (int j = 0; j < 8; ++j){ s += o[j]; s2 += o[j]*o[j]; }
  #pragma unroll
  for (int m = 1; m < 64; m <<= 1){ s += __shfl_xor(s, m); s2 += __shfl_xor(s2, m); }
  const float mu2 = s * (1.f/512.f);
  const float rstd2 = rsqrtf(s2 * (1.f/512.f) - mu2*mu2 + 1e-5f);
  float4 uv0 = *(const float4*)(u + n0), uv1 = *(const float4*)(u + n0 + 4);
  float4 vv0 = *(const float4*)(v + n0), vv1 = *(const float4*)(v + n0 + 4);
  float4 g20v = *(const float4*)(g2 + n0), g21v = *(const float4*)(g2 + n0 + 4);
  float4 b20v = *(const float4*)(b2 + n0), b21v = *(const float4*)(b2 + n0 + 4);
  float y[8];
  #pragma unroll
  for (int j = 0; j < 4; ++j){
    const float lin0 = rstd2 * (p[j]   - mu2 * ((const float*)&uv0)[j]) + ((const float*)&vv0)[j];
    const float lin1 = rstd2 * (p[4+j] - mu2 * ((const float*)&uv1)[j]) + ((const float*)&vv1)[j];
    const float oln0 = (o[j]   - mu2) * rstd2 * ((const float*)&g20v)[j] + ((const float*)&b20v)[j];
    const float oln1 = (o[4+j] - mu2) * rstd2 * ((const float*)&g21v)[j] + ((const float*)&b21v)[j];
    y[j]   = oln0 + lin0;
    y[4+j] = oln1 + lin1;
  }
  float t1 = 0.f, t2 = 0.f;
  #pragma unroll
  for (int j = 0; j < 8; ++j){ t1 += y[j]; t2 += y[j]*y[j]; }
  #pragma unroll
  for (int m = 1; m < 64; m <<= 1){ t1 += __shfl_xor(t1, m); t2 += __shfl_xor(t2, m); }
  const float mu3 = t1 * (1.f/512.f);
  const float rstd3 = rsqrtf(t2 * (1.f/512.f) - mu3*mu3 + 1e-5f);
  float4 g30v = *(const float4*)(g3 + n0), g31v = *(const float4*)(g3 + n0 + 4);
  float4 b30v = *(const float4*)(b3 + n0), b31v = *(const float4*)(b3 + n0 + 4);
  float4 r0, r1;
  #pragma unroll
  for (int j = 0; j < 4; ++j){
    ((float*)&r0)[j] = (y[j]   - mu3) * rstd3 * ((const float*)&g30v)[j] + ((const float*)&b30v)[j];
    ((float*)&r1)[j] = (y[4+j] - mu3) * rstd3 * ((const float*)&g31v)[j] + ((const float*)&b31v)[j];
  }
  *(float4*)(out + row * 512 + n0)     = r0;
  *(float4*)(out + row * 512 + n0 + 4) = r1;
}

extern "C" void kernel_launch(void* const* d_in, const int* in_sizes, int n_in,
                              void* d_out, int out_size, void* d_ws, size_t ws_size,
                              hipStream_t stream){
  const float* video = (const float*)d_in[0];
  const float* music = (const float*)d_in[1];
  const int*   mask  = (const int*)d_in[2];
  const float* ln1g  = (const float*)d_in[3];
  const float* ln1b  = (const float*)d_in[4];
  const float* Wq = (const float*)d_in[5];  const float* bq = (const float*)d_in[6];
  const float* Wk = (const float*)d_in[7];
  const float* Wv = (const float*)d_in[9];  const float* bv = (const float*)d_in[10];
  const float* Wo = (const float*)d_in[11]; const float* bo = (const float*)d_in[12];
  const float* Wl = (const float*)d_in[13]; const float* bl = (const float*)d_in[14];
  const float* g2 = (const float*)d_in[15]; const float* b2 = (const float*)d_in[16];
  const float* g3 = (const float*)d_in[17]; const float* b3 = (const float*)d_in[18];

  // d_out: mln at top [192M,256M); C/out occupy [0,256M) written ascending so
  // every chunk's writes stay strictly below all not-yet-consumed mln bytes.
  char* ob = (char*)d_out;
  unsigned short* mln  = (unsigned short*)(ob + 201326592);     // [65536][512] bf16
  unsigned short* Cb   = (unsigned short*)ob;                   // [131072][1024] bf16
  float* outp = (float*)d_out;

  char* wsb = (char*)d_ws;
  unsigned short* vbt    = (unsigned short*)wsb;                // [512][1024][128] bf16 (134MB)
  unsigned short* Wq_bf  = (unsigned short*)(wsb + 134217728);
  unsigned short* Bcat   = Wq_bf + 262144;                      // [1024][512]: Wo ; W2
  unsigned short* wlp    = Bcat + 524288;
  unsigned short* WoT    = wlp + 262144;
  unsigned short* WkT    = WoT + 262144;
  unsigned short* WvT    = WkT + 262144;
  unsigned short* Wvb    = WvT + 262144;                        // [1024][512]
  unsigned short* q_ws   = Wvb + 524288;                        // [256][512]
  unsigned short* q2_ws  = q_ws + 131072;                       // [256][512]
  unsigned short* vln    = q2_ws + 131072;                      // [256][512]
  unsigned short* mln_cp = vln + 131072;                        // [8*128][512] tail copy
  float* bias_cat = (float*)(mln_cp + 524288);                  // [1024]
  float* u_vec    = bias_cat + 1024;                            // [512]
  float* v_vec    = u_vec + 512;                                // [512]

  // ---- weight prep ----
  cvt2_f32_bf16<<<512, 256, 0, stream>>>(Wq, Wq_bf, Wo, Bcat);  // Bcat rows 0..511 = Wo
  ln_weight_prep<<<128, 256, 0, stream>>>(Wl, g2, b2, bl, bo, wlp, u_vec, v_vec, bias_cat);
  transpose3_bf<<<dim3(8, 8, 3), 256, 0, stream>>>(Wo, WoT, Wk, WkT, Wv, WvT);
  gemm_bt<<<dim3(4, 4), 256, 0, stream>>>(wlp, WoT, nullptr, Bcat + 262144, 0); // W2
  gemm_bt<<<dim3(4, 8), 256, 0, stream>>>(Bcat, WvT, nullptr, Wvb, 0);          // Wvb = Bcat*Wv
  cvb_add<<<256, 256, 0, stream>>>(Bcat, bv, bias_cat);

  // ---- activations ----
  ln_rows<<<16384, 256, 0, stream>>>(music, ln1g, ln1b, mln, 65536);
  ln_rows<<<64,    256, 0, stream>>>(video, ln1g, ln1b, vln, 256);
  gemm_bt<<<dim3(4, 2), 256, 0, stream>>>(vln, Wq_bf, bq, q_ws, 0);      // q
  gemm_bt<<<dim3(4, 2), 256, 0, stream>>>(q_ws, WkT, nullptr, q2_ws, 0); // q2 = q*Wk

  // ---- chunk-interleaved producer-consumer: vb97 chunk -> attn_c -> LN.
  const int vm0[5] = {0, 128, 256, 384, 480};
  const int vdm[5] = {128, 128, 128, 96, 32};   // vb97 covers all 512 m
  const int am0[5] = {0, 128, 256, 384, 480};
  const int adm[5] = {128, 128, 128, 96, 24};   // attn stops at 504 (tail below)
  for (int cidx = 0; cidx < 5; ++cidx){
    vb97<<<vdm[cidx] * 8, 256, 0, stream>>>(mln, Wvb, vbt, vm0[cidx]);
    const int m0 = am0[cidx], dm = adm[cidx];
    attn_c<<<dm * 4, 256, 0, stream>>>(q2_ws, mln, 0, vbt, mask, Cb, m0);
    ln_epilogue<<<dm * 64, 256, 0, stream>>>(Cb + (long)m0*256*1024,
                                             outp + (long)m0*256*512,
                                             bias_cat, u_vec, v_vec, g2, b2, g3, b3);
  }
  // tail m=504..511: its C writes overlap mln[480..512) -> use a copy
  copy_bf<<<256, 256, 0, stream>>>(mln + (long)504*128*512, mln_cp);
  attn_c<<<32, 256, 0, stream>>>(q2_ws, mln_cp, 504, vbt, mask, Cb, 504);
  ln_epilogue<<<512, 256, 0, stream>>>(Cb + (long)504*256*1024,
                                       outp + (long)504*256*512,
                                       bias_cat, u_vec, v_vec, g2, b2, g3, b3);
}